// Round 2
// baseline (590.375 us; speedup 1.0000x reference)
//
#include <hip/hip_runtime.h>
#include <math.h>

// ---------------------------------------------------------------------------
// APQBAttention on MI355X (gfx950), round 1 (resubmit; round 0 never ran —
// GPU acquisition timeout).
//   - per-head angular bias is constant along softmax axis -> dropped (invariant)
//   - dropout: mask numerator only; denominator = plain softmax sum; /cdrop folded
//     into final normalization
//   - fp16 MFMA (16x16x32) for all 4 GEMMs + flash attention
//   - T_mean computed in fp64 once (mask boundary exactness vs np reference)
// ---------------------------------------------------------------------------

typedef _Float16 f16;
typedef _Float16 f16x8 __attribute__((ext_vector_type(8)));
typedef float    f32x4 __attribute__((ext_vector_type(4)));

constexpr int EMB = 1024;
constexpr int NH  = 16;
constexpr int HD  = 64;
constexpr int NB  = 4;
constexpr int SEQ = 1024;
constexpr int MT  = NB * SEQ;   // 4096 rows

// workspace layout (bytes); total = 48 MB + 256 B
constexpr size_t WS_SC  = 0;                         // scalars (64B used)
constexpr size_t WS_XH  = 256;
constexpr size_t SZ_XH  = (size_t)MT * EMB * 2;      // 8 MB
constexpr size_t SZ_W   = (size_t)EMB * EMB * 2;     // 2 MB
constexpr size_t WS_WQH = WS_XH + SZ_XH;
constexpr size_t WS_WKH = WS_WQH + SZ_W;
constexpr size_t WS_WVH = WS_WKH + SZ_W;
constexpr size_t WS_WOH = WS_WVH + SZ_W;
constexpr size_t SZ_QH  = (size_t)NB * NH * SEQ * HD * 2;  // 8 MB
constexpr size_t WS_QH  = WS_WOH + SZ_W;
constexpr size_t WS_KH  = WS_QH + SZ_QH;
constexpr size_t WS_VTH = WS_KH + SZ_QH;             // V stored [B,H,D,T]
constexpr size_t WS_OA  = WS_VTH + SZ_QH;            // attn out [B,T,E] f16

#define MFMA16(a,b,c) __builtin_amdgcn_mfma_f32_16x16x32_f16((a),(b),(c),0,0,0)

// ---- scalar setup: T_mean (fp64) and 1/cdrop ------------------------------
__global__ void k_setup(const float* __restrict__ theta, float* __restrict__ sc) {
  if (threadIdx.x == 0 && blockIdx.x == 0) {
    double acc = 0.0;
    for (int h = 0; h < NH; ++h) {
      double th = (double)theta[h];
      th = 1.0 / (1.0 + exp(-th)) * (M_PI * 0.5);   // sigmoid * pi/2
      acc += fabs(sin(2.0 * th));
    }
    double tm = acc / (double)NH;
    sc[0] = (float)tm;
    sc[1] = (float)(1.0 / (1.0 - tm + 1e-8));       // inv cdrop
    ((double*)(sc + 2))[0] = tm;                    // fp64 copy for mask compare
  }
}

// ---- f32 -> f16 convert, 8 elems/thread -----------------------------------
__global__ void k_cvt8(const float* __restrict__ src, f16* __restrict__ dst, int n8) {
  int i = blockIdx.x * blockDim.x + threadIdx.x;
  if (i >= n8) return;
  const float4* s = (const float4*)src + 2 * (size_t)i;
  float4 a = s[0], b = s[1];
  f16x8 o;
  o[0] = (f16)a.x; o[1] = (f16)a.y; o[2] = (f16)a.z; o[3] = (f16)a.w;
  o[4] = (f16)b.x; o[5] = (f16)b.y; o[6] = (f16)b.z; o[7] = (f16)b.w;
  *(f16x8*)(dst + 8 * (size_t)i) = o;
}

// ---- GEMM: C[M,N] = A[M,K] * W[N,K]^T + bias ------------------------------
// 128x128 tile, BK=32, 4 waves (2x2), each wave 64x64 via 4x4 16x16x32 MFMAs.
// OUTMODE 0: f16 out to [B,H,T,D]   (Q, K)
// OUTMODE 1: f16 out to [B,H,D,T]   (V transposed for PV B-frags)
// OUTMODE 2: f32 out to [M,N]       (final projection -> d_out)
template <int OUTMODE>
__global__ __launch_bounds__(256) void k_gemm(
    const f16* __restrict__ A, const f16* __restrict__ Bw,
    const float* __restrict__ bias, void* __restrict__ outp)
{
  __shared__ f16 As[128 * 32];
  __shared__ f16 Bs[128 * 32];
  const int tid  = threadIdx.x;
  const int wave = tid >> 6, lane = tid & 63;
  const int c = lane & 15, g = lane >> 4;
  const int wr = wave >> 1, wc = wave & 1;
  const int bn0 = blockIdx.x * 128;
  const int bm0 = blockIdx.y * 128;

  const int srow = tid >> 2;        // 0..63 (staging row; +64 for 2nd chunk)
  const int scol = (tid & 3) * 8;   // f16 offset within BK=32

  f32x4 acc[4][4];
  #pragma unroll
  for (int i = 0; i < 4; ++i)
    #pragma unroll
    for (int j = 0; j < 4; ++j) acc[i][j] = (f32x4){0.f, 0.f, 0.f, 0.f};

  const f16* Ap = A  + (size_t)bm0 * EMB;
  const f16* Bp = Bw + (size_t)bn0 * EMB;

  for (int k0 = 0; k0 < EMB; k0 += 32) {
    int4 ra0 = *(const int4*)(Ap + (size_t)srow        * EMB + k0 + scol);
    int4 ra1 = *(const int4*)(Ap + (size_t)(srow + 64) * EMB + k0 + scol);
    int4 rb0 = *(const int4*)(Bp + (size_t)srow        * EMB + k0 + scol);
    int4 rb1 = *(const int4*)(Bp + (size_t)(srow + 64) * EMB + k0 + scol);
    __syncthreads();   // previous iteration's ds_reads complete before overwrite
    *(int4*)(As + srow * 32 + scol)        = ra0;
    *(int4*)(As + (srow + 64) * 32 + scol) = ra1;
    *(int4*)(Bs + srow * 32 + scol)        = rb0;
    *(int4*)(Bs + (srow + 64) * 32 + scol) = rb1;
    __syncthreads();

    f16x8 af[4], bf[4];
    #pragma unroll
    for (int mi = 0; mi < 4; ++mi)
      af[mi] = *(const f16x8*)(As + (wr * 64 + mi * 16 + c) * 32 + g * 8);
    #pragma unroll
    for (int nj = 0; nj < 4; ++nj)
      bf[nj] = *(const f16x8*)(Bs + (wc * 64 + nj * 16 + c) * 32 + g * 8);
    #pragma unroll
    for (int mi = 0; mi < 4; ++mi)
      #pragma unroll
      for (int nj = 0; nj < 4; ++nj)
        acc[mi][nj] = MFMA16(af[mi], bf[nj], acc[mi][nj]);
  }

  // epilogue: D layout row=(lane>>4)*4+i, col=lane&15
  #pragma unroll
  for (int mi = 0; mi < 4; ++mi) {
    #pragma unroll
    for (int nj = 0; nj < 4; ++nj) {
      #pragma unroll
      for (int i = 0; i < 4; ++i) {
        int row = bm0 + wr * 64 + mi * 16 + g * 4 + i;   // b*SEQ + t
        int col = bn0 + wc * 64 + nj * 16 + c;           // feature f
        float v = acc[mi][nj][i] + bias[col];
        if (OUTMODE == 2) {
          ((float*)outp)[(size_t)row * EMB + col] = v;
        } else {
          int b = row >> 10, t = row & 1023;
          int h = col >> 6,  d = col & 63;
          size_t idx;
          if (OUTMODE == 0) idx = (((size_t)(b * NH + h)) * SEQ + t) * HD + d;
          else              idx = (((size_t)(b * NH + h)) * HD  + d) * SEQ + t;
          ((f16*)outp)[idx] = (f16)v;
        }
      }
    }
  }
}

// ---- flash attention: one wave per 16 Q rows, KV tiles of 64 --------------
__global__ __launch_bounds__(256) void k_attn(
    const f16* __restrict__ Q, const f16* __restrict__ K, const f16* __restrict__ Vt,
    const float* __restrict__ noise, const float* __restrict__ sc,
    f16* __restrict__ Oa)
{
  __shared__ f16 Pl[4][16 * 72];   // per-wave P tile, stride 72 (2-way banks)
  const int tid  = threadIdx.x;
  const int wave = tid >> 6, lane = tid & 63;
  const int c = lane & 15, g = lane >> 4;
  const int bh = blockIdx.y;                 // b*NH + h
  const int b  = bh >> 4, h = bh & 15;
  const int q0 = blockIdx.x * 64 + wave * 16;

  const double tmean    = *(const double*)(sc + 2);
  const float inv_cdrop = sc[1];

  const f16* Qp   = Q  + ((size_t)bh * SEQ + q0) * HD;
  const f16* Kp   = K  + (size_t)bh * SEQ * HD;
  const f16* Vp   = Vt + (size_t)bh * HD * SEQ;
  const float* Np = noise + (size_t)bh * SEQ * SEQ;

  // Q A-frags (loop invariant): A[row=c][k = kc*32 + g*8 + j]
  f16x8 qa[2];
  qa[0] = *(const f16x8*)(Qp + c * HD + g * 8);
  qa[1] = *(const f16x8*)(Qp + c * HD + 32 + g * 8);

  f32x4 oacc[4];
  #pragma unroll
  for (int n = 0; n < 4; ++n) oacc[n] = (f32x4){0.f, 0.f, 0.f, 0.f};
  float mrun[4], lrun[4];
  #pragma unroll
  for (int i = 0; i < 4; ++i) { mrun[i] = -1e30f; lrun[i] = 0.f; }

  f16* myP = &Pl[wave][0];

  for (int s0 = 0; s0 < SEQ; s0 += 64) {
    // ---- S = Q K^T (16 x 64) ----
    f32x4 sa[4];
    #pragma unroll
    for (int n = 0; n < 4; ++n) sa[n] = (f32x4){0.f, 0.f, 0.f, 0.f};
    #pragma unroll
    for (int kc = 0; kc < 2; ++kc) {
      #pragma unroll
      for (int n = 0; n < 4; ++n) {
        f16x8 kb = *(const f16x8*)(Kp + (size_t)(s0 + n * 16 + c) * HD + kc * 32 + g * 8);
        sa[n] = MFMA16(qa[kc], kb, sa[n]);
      }
    }
    #pragma unroll
    for (int n = 0; n < 4; ++n)
      #pragma unroll
      for (int i = 0; i < 4; ++i) sa[n][i] *= 0.125f;   // 1/sqrt(64)

    // ---- online softmax (rows live at (g,i) across 16 lanes of c) ----
    float rmx[4];
    #pragma unroll
    for (int i = 0; i < 4; ++i)
      rmx[i] = fmaxf(fmaxf(sa[0][i], sa[1][i]), fmaxf(sa[2][i], sa[3][i]));
    #pragma unroll
    for (int off = 1; off < 16; off <<= 1)
      #pragma unroll
      for (int i = 0; i < 4; ++i)
        rmx[i] = fmaxf(rmx[i], __shfl_xor(rmx[i], off, 64));

    float al[4], rs[4];
    #pragma unroll
    for (int i = 0; i < 4; ++i) {
      float mn = fmaxf(mrun[i], rmx[i]);
      al[i] = __expf(mrun[i] - mn);
      mrun[i] = mn;
      rs[i] = 0.f;
    }
    #pragma unroll
    for (int n = 0; n < 4; ++n)
      #pragma unroll
      for (int i = 0; i < 4; ++i) {
        float p = __expf(sa[n][i] - mrun[i]);
        sa[n][i] = p;                 // unmasked p
        rs[i] += p;
      }
    #pragma unroll
    for (int off = 1; off < 16; off <<= 1)
      #pragma unroll
      for (int i = 0; i < 4; ++i)
        rs[i] += __shfl_xor(rs[i], off, 64);
    #pragma unroll
    for (int i = 0; i < 4; ++i) lrun[i] = lrun[i] * al[i] + rs[i];
    #pragma unroll
    for (int n = 0; n < 4; ++n)
      #pragma unroll
      for (int i = 0; i < 4; ++i) oacc[n][i] *= al[i];

    // ---- dropout mask + stage P (D-frag -> [row][col] LDS) ----
    #pragma unroll
    for (int i = 0; i < 4; ++i) {
      int trow = q0 + g * 4 + i;
      const float* nrow = Np + (size_t)trow * SEQ + s0;
      #pragma unroll
      for (int n = 0; n < 4; ++n) {
        float nz = nrow[n * 16 + c];
        float p  = ((double)nz > tmean) ? sa[n][i] : 0.f;
        myP[(g * 4 + i) * 72 + n * 16 + c] = (f16)p;
      }
    }
    asm volatile("s_waitcnt lgkmcnt(0)" ::: "memory");  // wave-internal LDS visibility

    // ---- O += P V  (A-frag of P from LDS, B-frag of V from global [D,T]) ----
    #pragma unroll
    for (int kc = 0; kc < 2; ++kc) {
      f16x8 pa = *(const f16x8*)(myP + c * 72 + kc * 32 + g * 8);
      #pragma unroll
      for (int n = 0; n < 4; ++n) {
        f16x8 vb = *(const f16x8*)(Vp + (size_t)(n * 16 + c) * SEQ + s0 + kc * 32 + g * 8);
        oacc[n] = MFMA16(pa, vb, oacc[n]);
      }
    }
  }

  // ---- normalize (1/l * 1/cdrop) and store [B,T,E] f16 ----
  #pragma unroll
  for (int i = 0; i < 4; ++i) {
    float isc = inv_cdrop / lrun[i];
    int trow = q0 + g * 4 + i;
    f16* orow = Oa + ((size_t)b * SEQ + trow) * EMB + h * HD;
    #pragma unroll
    for (int n = 0; n < 4; ++n)
      orow[n * 16 + c] = (f16)(oacc[n][i] * isc);
  }
}

// ---------------------------------------------------------------------------
extern "C" void kernel_launch(void* const* d_in, const int* in_sizes, int n_in,
                              void* d_out, int out_size, void* d_ws, size_t ws_size,
                              hipStream_t stream) {
  const float* x     = (const float*)d_in[0];
  const float* noise = (const float*)d_in[1];
  const float* Wq    = (const float*)d_in[2];
  const float* bq    = (const float*)d_in[3];
  const float* Wk    = (const float*)d_in[4];
  const float* bk    = (const float*)d_in[5];
  const float* Wv    = (const float*)d_in[6];
  const float* bv    = (const float*)d_in[7];
  const float* Wo    = (const float*)d_in[8];
  const float* bo    = (const float*)d_in[9];
  const float* theta = (const float*)d_in[10];
  // d_in[11] = corr_w: softmax-invariant per-head constant -> unused

  char* ws = (char*)d_ws;
  float* sc  = (float*)(ws + WS_SC);
  f16* xh    = (f16*)(ws + WS_XH);
  f16* wqh   = (f16*)(ws + WS_WQH);
  f16* wkh   = (f16*)(ws + WS_WKH);
  f16* wvh   = (f16*)(ws + WS_WVH);
  f16* woh   = (f16*)(ws + WS_WOH);
  f16* Qh    = (f16*)(ws + WS_QH);
  f16* Kh    = (f16*)(ws + WS_KH);
  f16* Vth   = (f16*)(ws + WS_VTH);
  f16* Oah   = (f16*)(ws + WS_OA);

  k_setup<<<1, 64, 0, stream>>>(theta, sc);

  k_cvt8<<<(MT * EMB / 8 + 255) / 256, 256, 0, stream>>>(x, xh, MT * EMB / 8);
  k_cvt8<<<(EMB * EMB / 8 + 255) / 256, 256, 0, stream>>>(Wq, wqh, EMB * EMB / 8);
  k_cvt8<<<(EMB * EMB / 8 + 255) / 256, 256, 0, stream>>>(Wk, wkh, EMB * EMB / 8);
  k_cvt8<<<(EMB * EMB / 8 + 255) / 256, 256, 0, stream>>>(Wv, wvh, EMB * EMB / 8);
  k_cvt8<<<(EMB * EMB / 8 + 255) / 256, 256, 0, stream>>>(Wo, woh, EMB * EMB / 8);

  dim3 gemm_grid(EMB / 128, MT / 128);   // (8, 32)
  k_gemm<0><<<gemm_grid, 256, 0, stream>>>(xh, wqh, bq, (void*)Qh);
  k_gemm<0><<<gemm_grid, 256, 0, stream>>>(xh, wkh, bk, (void*)Kh);
  k_gemm<1><<<gemm_grid, 256, 0, stream>>>(xh, wvh, bv, (void*)Vth);

  k_attn<<<dim3(SEQ / 64, NB * NH), 256, 0, stream>>>(Qh, Kh, Vth, noise, sc, Oah);

  k_gemm<2><<<gemm_grid, 256, 0, stream>>>(Oah, woh, bo, d_out);
}